// Round 9
// baseline (530.139 us; speedup 1.0000x reference)
//
#include <hip/hip_runtime.h>
#include <hip/hip_bf16.h>
#include <math.h>

typedef __attribute__((ext_vector_type(8))) short bf16x8;
typedef __attribute__((ext_vector_type(4))) float f32x4;
typedef __attribute__((ext_vector_type(4))) unsigned int u32x4;

#define NP 16384
#define HWFULL 65536

__device__ __forceinline__ unsigned short f2bf(float f){
    union { float f; unsigned int u; } v; v.f = f;
    unsigned int u = v.u;
    u += 0x7fffu + ((u >> 16) & 1u);
    return (unsigned short)(u >> 16);
}
__device__ __forceinline__ float bf2f(unsigned short h){
    union { unsigned int u; float f; } v; v.u = ((unsigned int)h) << 16;
    return v.f;
}
// HW packed bf16 convert (RNE, identical rounding to f2bf): 1 instr vs ~10
__device__ __forceinline__ unsigned int pk2(float a, float b){
    unsigned int r;
    asm("v_cvt_pk_bf16_f32 %0, %1, %2" : "=v"(r) : "v"(a), "v"(b));
    return r;
}

// ---- K0: fp32 -> bf16 weight conversion (qkv + proj in one launch) ----
__global__ void k_convert2(const float* __restrict__ qw, const float* __restrict__ pw,
                           unsigned short* __restrict__ Wbf, unsigned short* __restrict__ Pbf){
    int i = blockIdx.x * 256 + threadIdx.x;
    if (i < 110592) Wbf[i] = f2bf(qw[i]);
    else if (i < 110592 + 36864) Pbf[i - 110592] = f2bf(pw[i - 110592]);
}

// ---- K1: qkv 1x1 conv (bf16 MFMA GEMM) fused with 2x2 maxpool ----
// v4 structure (measured fixed point ~170us across 5 variants — do not retune).
// grid (512, 4): bx -> (y2 = bx>>2, x2blk = bx&3); by = b
__global__ __launch_bounds__(256, 2)
void k_qkvpool(const float* __restrict__ x, const unsigned short* __restrict__ Wbf,
               unsigned short* __restrict__ qkvp){
    __shared__ unsigned short Bl[128*200];  // [pos][K=192 + pad8] bf16, persistent
    __shared__ unsigned short Ep[192*36];   // pooled epilogue buffer
    int tid = threadIdx.x;
    int lane = tid & 63, wv = tid >> 6;
    int n16 = lane & 15, quad = lane >> 4;
    int bx = blockIdx.x;
    int y2 = bx >> 2, x2blk = bx & 3;
    int b = blockIdx.y;

    // ---- stage B: transpose-gather x[ic][pos] -> Bl[pos][ic], fp32->bf16, full K ----
    #pragma unroll 6
    for (int j=0;j<12;j++){
        int idx = tid + j*256;
        int g = idx >> 7, w = idx & 127;       // g: ic granule of 8; w: 0..63 row y, 64..127 row y+1
        int y = y2*2 + (w >> 6);
        int xc = x2blk*64 + (w & 63);
        const float* xp = x + (size_t)(b*192 + g*8) * HWFULL + y*256 + xc;
        float v0 = xp[0];
        float v1 = xp[(size_t)1*HWFULL];
        float v2 = xp[(size_t)2*HWFULL];
        float v3 = xp[(size_t)3*HWFULL];
        float v4 = xp[(size_t)4*HWFULL];
        float v5 = xp[(size_t)5*HWFULL];
        float v6 = xp[(size_t)6*HWFULL];
        float v7 = xp[(size_t)7*HWFULL];
        u32x4 pk;
        pk.x = pk2(v0,v1); pk.y = pk2(v2,v3); pk.z = pk2(v4,v5); pk.w = pk2(v6,v7);
        *(u32x4*)&Bl[w*200 + g*8] = pk;
    }
    // preload A fragments for (ocblk=0, it=0) — independent of LDS
    bf16x8 afc[3], afn[3];
    #pragma unroll
    for (int j=0;j<3;j++)
        afc[j] = *(const bf16x8*)(Wbf + (size_t)(((wv*3+j)*16 + n16)*192 + quad*8));
    __syncthreads();

    for (int ocblk=0; ocblk<3; ocblk++){
        f32x4 acc[3][8];
        #pragma unroll
        for (int j=0;j<3;j++)
          #pragma unroll
          for (int s=0;s<8;s++)
            acc[j][s] = (f32x4){0.f,0.f,0.f,0.f};

        #pragma unroll 1
        for (int it=0; it<6; it++){
            int nocb = (it==5) ? ocblk+1 : ocblk;
            int nit  = (it==5) ? 0 : it+1;
            if (nocb < 3){
                #pragma unroll
                for (int j=0;j<3;j++)
                    afn[j] = *(const bf16x8*)(Wbf +
                        (size_t)((nocb*192 + (wv*3+j)*16 + n16)*192 + nit*32 + quad*8));
            }
            int bko = it*32 + quad*8;
            bf16x8 bfr[8];
            #pragma unroll
            for (int s=0;s<8;s++) bfr[s] = *(const bf16x8*)&Bl[(s*16 + n16)*200 + bko];
            #pragma unroll
            for (int j=0;j<3;j++)
              #pragma unroll
              for (int s=0;s<8;s++)
                acc[j][s] = __builtin_amdgcn_mfma_f32_16x16x32_bf16(afc[j], bfr[s], acc[j][s], 0,0,0);
            #pragma unroll
            for (int j=0;j<3;j++) afc[j] = afn[j];
        }
        __syncthreads();   // prev ocblk's cooperative-store reads of Ep done
        // ---- epilogue: 2x2 maxpool into LDS (strip sp & sp+4 = rows y,y+1; lane^1 = x,x+1)
        #pragma unroll
        for (int j=0;j<3;j++){
            int ocr = (wv*3+j)*16 + quad*4;
            #pragma unroll
            for (int sp=0;sp<4;sp++){
                #pragma unroll
                for (int r=0;r<4;r++){
                    float v = fmaxf(acc[j][sp][r], acc[j][sp+4][r]);
                    float o = __shfl_xor(v, 1, 64);
                    v = fmaxf(v, o);
                    if ((n16 & 1) == 0)
                        Ep[(ocr + r)*36 + sp*8 + (n16 >> 1)] = f2bf(v);
                }
            }
        }
        __syncthreads();
        // ---- cooperative coalesced store: 192 rows x 32 shorts (64B/row) ----
        size_t rowbase = (size_t)(b*576 + ocblk*192)*NP + y2*128 + x2blk*32;
        #pragma unroll
        for (int it2=0; it2<6; it2++){
            int c = tid + it2*256;
            int row = c >> 3, seg = c & 7;
            uint2 vv = *(const uint2*)&Ep[row*36 + seg*4];
            *(uint2*)(qkvp + rowbase + (size_t)row*NP + seg*4) = vv;
        }
    }
}

// ---- K2a: FUSED dwconv(q,k) + gram + sumsq. ----
// q,k dwconv outputs never touch HBM: conv in regs (fp32), RNE-pack to LDS tile
// (bit-identical to old dwout store), then attnraw-v5 MFMA gram phase.
// Saves 50MB write + 50MB read. grid (64, 6, 4), block 256.
__global__ __launch_bounds__(256) void k_qkgram(const unsigned short* __restrict__ qkvp,
                                                const float* __restrict__ dww,
                                                float* __restrict__ attn,
                                                float* __restrict__ sumsq){
    __shared__ unsigned short sq[32*264];   // conv'd q tile [32ch][256pos]
    __shared__ unsigned short sk[32*264];
    __shared__ float red[4][32][33];        // 16.9 KB
    int tid = threadIdx.x;
    int h = blockIdx.y, b = blockIdx.z;
    int y0 = blockIdx.x * 2;                // image rows y0, y0+1 (of 128)
    int cc = tid >> 2, sub = tid & 3;       // cc: 0..31 q-ch, 32..63 k-ch
    int chg = (cc < 32) ? (h*32 + cc) : (192 + h*32 + (cc - 32));
    const unsigned short* img = qkvp + (size_t)(b*576 + chg)*NP;  // 128x128 bf16
    float w[9];
    #pragma unroll
    for (int i=0;i<9;i++) w[i] = dww[chg*9 + i];
    unsigned short* dst = (cc < 32) ? sq : sk;
    int ccl = cc & 31;
    float ssq = 0.f;

    #pragma unroll 1
    for (int tt=0; tt<2; tt++){
        int st = sub*2 + tt;                // 0..7
        int r01 = st >> 2, qtr = st & 3;    // output row (0/1), col quarter (32 cols)
        int y = y0 + r01;
        int x0 = qtr*32;
        float acc[32];
        #pragma unroll
        for (int i=0;i<32;i++) acc[i] = 0.f;
        #pragma unroll
        for (int dy=0; dy<3; dy++){
            int ry = y - 1 + dy;
            float rowf[34];
            if (ry >= 0 && ry < 128){
                const unsigned short* rp = img + ry*128 + x0;
                rowf[0] = (x0 > 0) ? bf2f(rp[-1]) : 0.f;
                #pragma unroll
                for (int j=0;j<4;j++){
                    bf16x8 v = *(const bf16x8*)(rp + j*8);
                    #pragma unroll
                    for (int i=0;i<8;i++) rowf[1 + j*8 + i] = bf2f((unsigned short)v[i]);
                }
                rowf[33] = (x0 + 32 < 128) ? bf2f(rp[32]) : 0.f;
            } else {
                #pragma unroll
                for (int i=0;i<34;i++) rowf[i] = 0.f;
            }
            float wa = w[dy*3], wb = w[dy*3+1], wc = w[dy*3+2];
            #pragma unroll
            for (int i=0;i<32;i++)
                acc[i] += wa*rowf[i] + wb*rowf[i+1] + wc*rowf[i+2];
        }
        // ssq + RNE pack to LDS tile (same rounding as old dwout store)
        unsigned short* drow = dst + ccl*264 + r01*128 + x0;
        #pragma unroll
        for (int g8=0; g8<4; g8++){
            u32x4 pk;
            pk.x = pk2(acc[g8*8+0], acc[g8*8+1]);
            pk.y = pk2(acc[g8*8+2], acc[g8*8+3]);
            pk.z = pk2(acc[g8*8+4], acc[g8*8+5]);
            pk.w = pk2(acc[g8*8+6], acc[g8*8+7]);
            *(u32x4*)(drow + g8*8) = pk;
        }
        #pragma unroll
        for (int i=0;i<32;i++) ssq += acc[i]*acc[i];
    }
    // sumsq: reduce over the 4 threads (sub 0..3, same wave) sharing this channel
    ssq += __shfl_down(ssq, 1, 64);
    ssq += __shfl_down(ssq, 2, 64);
    if (sub == 0) atomicAdd(&sumsq[b*384 + chg], ssq);
    __syncthreads();

    // ---- phase B: gram MFMA (attnraw-v5 structure, tile-local) ----
    int lane = tid & 63, wv = tid >> 6;
    int n16 = lane & 15, quad = lane >> 4;
    f32x4 gac[2][2];
    #pragma unroll
    for (int i=0;i<2;i++)
      #pragma unroll
      for (int j=0;j<2;j++) gac[i][j] = (f32x4){0.f,0.f,0.f,0.f};

    #pragma unroll
    for (int ks=0; ks<2; ks++){
        int ko = wv*64 + ks*32 + quad*8;
        bf16x8 aq0 = *(const bf16x8*)&sq[n16*264 + ko];
        bf16x8 aq1 = *(const bf16x8*)&sq[(16+n16)*264 + ko];
        bf16x8 bk0 = *(const bf16x8*)&sk[n16*264 + ko];
        bf16x8 bk1 = *(const bf16x8*)&sk[(16+n16)*264 + ko];
        gac[0][0] = __builtin_amdgcn_mfma_f32_16x16x32_bf16(aq0, bk0, gac[0][0], 0,0,0);
        gac[0][1] = __builtin_amdgcn_mfma_f32_16x16x32_bf16(aq0, bk1, gac[0][1], 0,0,0);
        gac[1][0] = __builtin_amdgcn_mfma_f32_16x16x32_bf16(aq1, bk0, gac[1][0], 0,0,0);
        gac[1][1] = __builtin_amdgcn_mfma_f32_16x16x32_bf16(aq1, bk1, gac[1][1], 0,0,0);
    }
    // C layout: row = cc2*16 + quad*4 + r, col = dd*16 + n16
    #pragma unroll
    for (int cc2=0; cc2<2; cc2++)
      #pragma unroll
      for (int dd=0; dd<2; dd++)
        #pragma unroll
        for (int r=0; r<4; r++)
          red[wv][cc2*16 + quad*4 + r][dd*16 + n16] = gac[cc2][dd][r];
    __syncthreads();
    float* ap = attn + (size_t)(b*6+h)*1024;
    #pragma unroll
    for (int j=0;j<4;j++){
        int o = tid + j*256;
        int c = o >> 5, d = o & 31;
        float v = red[0][c][d] + red[1][c][d] + red[2][c][d] + red[3][c][d];
        atomicAdd(ap + o, v);
    }
}

// ---- K2b: depthwise 3x3 conv, V channels only (q,k handled by k_qkgram) ----
// grid (192, 4), block 256
__global__ __launch_bounds__(256) void k_dwv(const unsigned short* __restrict__ qkvp,
                                             const float* __restrict__ dww,
                                             unsigned short* __restrict__ dwoutB){
    __shared__ unsigned short sl[128*128];   // 32KB: whole channel image
    int tid = threadIdx.x;
    int chg = 384 + blockIdx.x;              // v channel
    int b = blockIdx.y;
    const unsigned short* in = qkvp + (size_t)(b*576 + chg)*NP;
    #pragma unroll
    for (int j=0;j<8;j++){
        int idx = tid + j*256;
        *(u32x4*)&sl[idx*8] = *(const u32x4*)(in + idx*8);
    }
    float w0 = dww[chg*9+0], w1 = dww[chg*9+1], w2 = dww[chg*9+2];
    float w3 = dww[chg*9+3], w4 = dww[chg*9+4], w5 = dww[chg*9+5];
    float w6 = dww[chg*9+6], w7 = dww[chg*9+7], w8 = dww[chg*9+8];
    __syncthreads();
    int c = tid & 127, half = tid >> 7;
    float mL = (c > 0) ? 1.f : 0.f, mR = (c < 127) ? 1.f : 0.f;
    int cm = (c > 0) ? c-1 : c, cp = (c < 127) ? c+1 : c;
    unsigned short* outp = dwoutB + (size_t)(b*576 + chg)*NP;
    int r0 = half*64;
    float r0a, r0b, r0c, r1a, r1b, r1c;
    if (half == 0){ r0a = r0b = r0c = 0.f; }
    else { int rr = r0-1;
           r0a = bf2f(sl[rr*128+cm])*mL; r0b = bf2f(sl[rr*128+c]); r0c = bf2f(sl[rr*128+cp])*mR; }
    { int rr = r0;
      r1a = bf2f(sl[rr*128+cm])*mL; r1b = bf2f(sl[rr*128+c]); r1c = bf2f(sl[rr*128+cp])*mR; }
    #pragma unroll 4
    for (int i=0;i<64;i++){
        int rr = r0 + i + 1;
        float r2a, r2b, r2c;
        if (rr < 128){
            r2a = bf2f(sl[rr*128+cm])*mL; r2b = bf2f(sl[rr*128+c]); r2c = bf2f(sl[rr*128+cp])*mR;
        } else { r2a = r2b = r2c = 0.f; }
        float a = r0a*w0 + r0b*w1 + r0c*w2
                + r1a*w3 + r1b*w4 + r1c*w5
                + r2a*w6 + r2b*w7 + r2c*w8;
        outp[(r0+i)*128 + c] = f2bf(a);
        r0a=r1a; r0b=r1b; r0c=r1c;
        r1a=r2a; r1b=r2b; r1c=r2c;
    }
}

// ---- K3b: normalize, temperature, 4x top-k masked softmax, combine ----
// grid 24, block 1024
__global__ void k_mask_softmax(const float* __restrict__ attn, const float* __restrict__ sumsq,
                               const float* __restrict__ temp,
                               const float* __restrict__ A1, const float* __restrict__ A2,
                               const float* __restrict__ A3, const float* __restrict__ A4,
                               float* __restrict__ comb){
    __shared__ float Am[32][33];
    __shared__ float qn[32], kn[32];
    int t = threadIdx.x;
    int bh = blockIdx.x;
    int b = bh / 6, h = bh % 6;
    if (t < 32) qn[t] = fmaxf(sqrtf(sumsq[b*384 + h*32 + t]), 1e-12f);
    else if (t >= 64 && t < 96) kn[t-64] = fmaxf(sqrtf(sumsq[b*384 + 192 + h*32 + (t-64)]), 1e-12f);
    __syncthreads();
    int c = t >> 5, d = t & 31;
    float tv = temp[h];
    float am = attn[(size_t)bh*1024 + t] * tv / (qn[c]*kn[d]);
    Am[c][d] = am;
    // row max (32-lane subgroups)
    float m = am;
    #pragma unroll
    for (int off=16; off>0; off>>=1) m = fmaxf(m, __shfl_down(m, off, 32));
    m = __shfl(m, 0, 32);
    float e = expf(am - m);
    __syncthreads();
    // exact rank (ties broken by index, matching top_k semantics)
    int rk = 0;
    #pragma unroll 8
    for (int dd=0; dd<32; dd++){
        float av = Am[c][dd];
        rk += (av > am) || (av == am && dd < d);
    }
    float e0 = rk < 16 ? e : 0.f;
    float e1 = rk < 21 ? e : 0.f;
    float e2 = rk < 24 ? e : 0.f;
    float e3 = rk < 25 ? e : 0.f;
    #pragma unroll
    for (int off=16; off>0; off>>=1){
        e0 += __shfl_down(e0, off, 32);
        e1 += __shfl_down(e1, off, 32);
        e2 += __shfl_down(e2, off, 32);
        e3 += __shfl_down(e3, off, 32);
    }
    float d0 = __shfl(e0, 0, 32), d1 = __shfl(e1, 0, 32);
    float d2 = __shfl(e2, 0, 32), d3 = __shfl(e3, 0, 32);
    float s = (rk<16 ? A1[0]/d0 : 0.f) + (rk<21 ? A2[0]/d1 : 0.f)
            + (rk<24 ? A3[0]/d2 : 0.f) + (rk<25 ? A4[0]/d3 : 0.f);
    comb[(size_t)bh*1024 + t] = e * s;
}

// ---- K4: FUSED applyv + proj: g = gelu(comb @ v) built in LDS (bf16), then
// proj GEMM + nearest-2x upsample. grid (128, 4), block 256. 2 blocks/CU.
__global__ __launch_bounds__(256, 2)
void k_avproj(const unsigned short* __restrict__ dwoutB, const float* __restrict__ comb,
              const unsigned short* __restrict__ Pbf, float* __restrict__ out){
    __shared__ unsigned short Bl[128*200];  // [pos][K=192 + pad8] = g in bf16
    __shared__ float cm[6144];              // comb, all 6 heads
    int tid = threadIdx.x;
    int y2 = blockIdx.x, b = blockIdx.y;

    // stage comb (24 KB)
    #pragma unroll
    for (int j=0;j<24;j++) cm[tid + j*256] = comb[b*6144 + tid + j*256];

    // ---- phase 1: g[128 pos][192 ch] into Bl. 2 threads/pos (3 heads each). ----
    int n_loc = tid & 127, half = tid >> 7;
    const unsigned short* vb = dwoutB + (size_t)(b*576 + 384 + half*96)*NP + y2*128 + n_loc;
    __syncthreads();   // cm ready
    #pragma unroll 1
    for (int hh=0; hh<3; hh++){
        float v[32];
        #pragma unroll
        for (int d=0; d<32; d++) v[d] = bf2f(vb[(size_t)(hh*32+d)*NP]);
        const float* chp = &cm[(half*3+hh)*1024];
        #pragma unroll 1
        for (int cg=0; cg<4; cg++){
            float s[8];
            #pragma unroll
            for (int i=0;i<8;i++){
                const float* crow = chp + (cg*8+i)*32;
                float acc = 0.f;
                #pragma unroll
                for (int d=0;d<32;d++) acc += crow[d]*v[d];
                s[i] = 0.5f*acc*(1.f + erff(acc*0.70710678118654752f));
            }
            u32x4 pk;
            pk.x = pk2(s[0],s[1]); pk.y = pk2(s[2],s[3]);
            pk.z = pk2(s[4],s[5]); pk.w = pk2(s[6],s[7]);
            *(u32x4*)&Bl[n_loc*200 + half*96 + hh*32 + cg*8] = pk;
        }
    }

    // ---- phase 2: proj GEMM (verbatim k_proj) ----
    int lane = tid & 63, wv = tid >> 6;
    int n16 = lane & 15, quad = lane >> 4;
    bf16x8 afc[3], afn[3];
    #pragma unroll
    for (int j=0;j<3;j++)
        afc[j] = *(const bf16x8*)(Pbf + (size_t)(((wv*3+j)*16 + n16)*192 + quad*8));
    __syncthreads();   // Bl ready

    f32x4 acc[3][8];
    #pragma unroll
    for (int j=0;j<3;j++)
      #pragma unroll
      for (int s=0;s<8;s++)
        acc[j][s] = (f32x4){0.f,0.f,0.f,0.f};

    #pragma unroll 1
    for (int it=0; it<6; it++){
        if (it < 5){
            #pragma unroll
            for (int j=0;j<3;j++)
                afn[j] = *(const bf16x8*)(Pbf +
                    (size_t)(((wv*3+j)*16 + n16)*192 + (it+1)*32 + quad*8));
        }
        int bko = it*32 + quad*8;
        bf16x8 bfr[8];
        #pragma unroll
        for (int s=0;s<8;s++) bfr[s] = *(const bf16x8*)&Bl[(s*16 + n16)*200 + bko];
        #pragma unroll
        for (int j=0;j<3;j++)
          #pragma unroll
          for (int s=0;s<8;s++)
            acc[j][s] = __builtin_amdgcn_mfma_f32_16x16x32_bf16(afc[j], bfr[s], acc[j][s], 0,0,0);
        #pragma unroll
        for (int j=0;j<3;j++) afc[j] = afn[j];
    }

    #pragma unroll
    for (int j=0;j<3;j++){
        int oc = (wv*3+j)*16 + quad*4;
        #pragma unroll
        for (int sp=0;sp<8;sp++){
            int x2 = sp*16 + n16;
            #pragma unroll
            for (int r=0;r<4;r++){
                float v = acc[j][sp][r];
                size_t o = ((size_t)(b*192 + oc + r)*256 + 2*y2)*256 + 2*x2;
                float2 val = make_float2(v, v);
                *(float2*)(out + o) = val;
                *(float2*)(out + o + 256) = val;
            }
        }
    }
}

extern "C" void kernel_launch(void* const* d_in, const int* in_sizes, int n_in,
                              void* d_out, int out_size, void* d_ws, size_t ws_size,
                              hipStream_t stream){
    const float* x     = (const float*)d_in[0];
    const float* temp  = (const float*)d_in[1];
    const float* qkvw  = (const float*)d_in[2];
    const float* dww   = (const float*)d_in[3];
    const float* projw = (const float*)d_in[4];
    const float* A1    = (const float*)d_in[5];
    const float* A2    = (const float*)d_in[6];
    const float* A3    = (const float*)d_in[7];
    const float* A4    = (const float*)d_in[8];
    float* out = (float*)d_out;
    char* ws = (char*)d_ws;

    // workspace layout (bytes)
    unsigned short* dwoutB = (unsigned short*)ws;                    // 75,497,472 (only v region used)
    unsigned short* qkvp   = (unsigned short*)(ws + 75497472ull);    // 75,497,472
    unsigned short* Wbf    = (unsigned short*)(ws + 150994944ull);   // 221,184
    unsigned short* Pbf    = (unsigned short*)(ws + 151216128ull);   // 73,728
    float*          attn   = (float*)(ws + 151289856ull);            // 98,304
    float*          comb   = (float*)(ws + 151388160ull);            // 98,304
    float*          sumsq  = (float*)(ws + 151486464ull);            // 6,144

    hipMemsetAsync(attn, 0, 98304, stream);
    hipMemsetAsync(sumsq, 0, 6144, stream);
    k_convert2<<<dim3((147456+255)/256), dim3(256), 0, stream>>>(qkvw, projw, Wbf, Pbf);
    k_qkvpool<<<dim3(512,4), dim3(256), 0, stream>>>(x, Wbf, qkvp);
    k_qkgram<<<dim3(64,6,4), dim3(256), 0, stream>>>(qkvp, dww, attn, sumsq);
    k_dwv<<<dim3(192,4), dim3(256), 0, stream>>>(qkvp, dww, dwoutB);
    k_mask_softmax<<<dim3(24), dim3(1024), 0, stream>>>(attn, sumsq, temp, A1, A2, A3, A4, comb);
    k_avproj<<<dim3(128,4), dim3(256), 0, stream>>>(dwoutB, comb, Pbf, out);
}